// Round 6
// baseline (84.366 us; speedup 1.0000x reference)
//
#include <hip/hip_runtime.h>
#include <hip/hip_bf16.h>

#define TT 2048
#define BATCH 8
#define MROWS (BATCH*TT)   // 16384
#define AW 8               // waves per attn block

typedef __attribute__((ext_vector_type(8))) short bf16x8;   // MFMA A/B frag (4 VGPR)
typedef __attribute__((ext_vector_type(4))) short s16x4;
typedef __attribute__((ext_vector_type(4))) float f32x4;    // MFMA C/D frag

__device__ __forceinline__ short f2bf(float f) {
    union { __hip_bfloat16 h; short s; } u;
    u.h = __float2bfloat16(f);
    return u.s;
}
__device__ __forceinline__ float bf2f(short s) {
    union { unsigned u; float f; } u;
    u.u = ((unsigned)(unsigned short)s) << 16;
    return u.f;
}

// ---------------------------------------------------------------------------
// W transpose: Wq|Wk|Wv [1024][64] f32 -> wt [192][1024] bf16 (row n = col of W)
// Wq gets scale = (1/32)*log2(e) folded in (softmax scale + exp->exp2).
// ---------------------------------------------------------------------------
__global__ __launch_bounds__(256) void wtrans_kernel(
    const float* __restrict__ Wk, const float* __restrict__ Wq,
    const float* __restrict__ Wv, short* __restrict__ wt)
{
    __shared__ float tile[64][68];
    const int mat = blockIdx.x >> 4;           // 0=q,1=k,2=v
    const int k0  = (blockIdx.x & 15) * 64;
    const float* W = (mat == 0) ? Wq : (mat == 1) ? Wk : Wv;
    const float scl = (mat == 0) ? 0.04508422002778011f : 1.0f;  // (1/32)*log2(e)
    const int t = threadIdx.x;
    const int row = t >> 2, quad = t & 3;
    #pragma unroll
    for (int i = 0; i < 4; i++) {
        float4 v = *(const float4*)(W + (size_t)(k0 + row) * 64 + quad * 16 + i * 4);
        *(float4*)&tile[row][quad * 16 + i * 4] = v;
    }
    __syncthreads();
    short tmp[16];
    #pragma unroll
    for (int j = 0; j < 16; j++) tmp[j] = f2bf(tile[quad * 16 + j][row] * scl);
    short* dst = wt + (size_t)(mat * 64 + row) * 1024 + k0 + quad * 16;
    #pragma unroll
    for (int j2 = 0; j2 < 2; j2++) {
        bf16x8 o;
        #pragma unroll
        for (int jj = 0; jj < 8; jj++) o[jj] = tmp[j2 * 8 + jj];
        *(bf16x8*)(dst + j2 * 8) = o;
    }
}

// ---------------------------------------------------------------------------
// Projection v3: barrier-free main loop, register-resident pipeline.
// 512 blocks x 4 waves; wave w owns cols [w*48, w*48+48) of 32 rows.
// A-frags loaded DIRECTLY from global x (no LDS, no per-step barrier);
// 2-deep x prefetch + 1-deep wt prefetch, fully unrolled k-loop.
// launch_bounds(256,2): VGPR cap 256 -> no squeeze-to-64 spills (R5 bug).
// ---------------------------------------------------------------------------
__device__ __forceinline__ void xload(float4 (&dst)[8], const float* xr, int kk) {
    #pragma unroll
    for (int rt = 0; rt < 2; rt++)
        #pragma unroll
        for (int kc = 0; kc < 2; kc++)
            #pragma unroll
            for (int h = 0; h < 2; h++)
                dst[rt * 4 + kc * 2 + h] =
                    *(const float4*)(xr + rt * 16 * 1024 + kk * 64 + kc * 32 + h * 4);
}
__device__ __forceinline__ void bload(bf16x8 (&dst)[3][2], const short* wb, int kk) {
    #pragma unroll
    for (int nt = 0; nt < 3; nt++)
        #pragma unroll
        for (int kc = 0; kc < 2; kc++)
            dst[nt][kc] = *(const bf16x8*)(wb + nt * 16 * 1024 + kk * 64 + kc * 32);
}

__global__ __launch_bounds__(256, 2) void proj_kernel(
    const float* __restrict__ x, const short* __restrict__ wt,
    short* __restrict__ qb, short* __restrict__ kb, short* __restrict__ vtb)
{
    __shared__ short vsl[32][66];
    const int tid  = threadIdx.x;
    const int lane = tid & 63, w = tid >> 6;
    const int l15  = lane & 15, g = lane >> 4;
    const int r0   = blockIdx.x * 32;

    const float* xr = x  + (size_t)(r0 + l15) * 1024 + g * 8;
    const short* wb = wt + (size_t)(w * 48 + l15) * 1024 + g * 8;

    f32x4 acc[2][3];
    #pragma unroll
    for (int rt = 0; rt < 2; rt++)
        #pragma unroll
        for (int nt = 0; nt < 3; nt++)
            acc[rt][nt] = (f32x4){0.f, 0.f, 0.f, 0.f};

    float4 xbuf[2][8];      // 2-deep x pipeline
    bf16x8 bbuf[2][3][2];   // 1-deep wt pipeline

    xload(xbuf[0], xr, 0);
    xload(xbuf[1], xr, 1);
    bload(bbuf[0], wb, 0);

    #pragma unroll
    for (int ks = 0; ks < 16; ks++) {
        const int cs = ks & 1, ns = cs ^ 1;

        // 1. convert current x stage to A-frags (frees xbuf[cs])
        bf16x8 af[2][2];
        #pragma unroll
        for (int rt = 0; rt < 2; rt++)
            #pragma unroll
            for (int kc = 0; kc < 2; kc++) {
                const float4 a = xbuf[cs][rt * 4 + kc * 2 + 0];
                const float4 b = xbuf[cs][rt * 4 + kc * 2 + 1];
                af[rt][kc] = (bf16x8){ f2bf(a.x), f2bf(a.y), f2bf(a.z), f2bf(a.w),
                                       f2bf(b.x), f2bf(b.y), f2bf(b.z), f2bf(b.w) };
            }
        // 2. prefetch x for ks+2 (hides L3 latency under 2 steps of work)
        if (ks + 2 < 16) xload(xbuf[cs], xr, ks + 2);
        // 3. prefetch wt for ks+1 (hides L2 latency under 1 step)
        if (ks + 1 < 16) bload(bbuf[ns], wb, ks + 1);
        // 4. MFMA
        #pragma unroll
        for (int kc = 0; kc < 2; kc++)
            #pragma unroll
            for (int rt = 0; rt < 2; rt++)
                #pragma unroll
                for (int nt = 0; nt < 3; nt++)
                    acc[rt][nt] = __builtin_amdgcn_mfma_f32_16x16x32_bf16(
                        af[rt][kc], bbuf[cs][nt][kc], acc[rt][nt], 0, 0, 0);
    }

    // epilogue: q,k direct; v staged to LDS for transposed coalesced write
    const int bi  = r0 >> 11;
    const int sl0 = r0 & 2047;
    #pragma unroll
    for (int rt = 0; rt < 2; rt++)
        #pragma unroll
        for (int nt = 0; nt < 3; nt++) {
            const int c = w * 48 + nt * 16 + l15;
            #pragma unroll
            for (int r = 0; r < 4; r++) {
                const int row = r0 + rt * 16 + g * 4 + r;
                const short v = f2bf(acc[rt][nt][r]);
                if (c < 64)        qb[(size_t)row * 64 + c] = v;
                else if (c < 128)  kb[(size_t)row * 64 + (c - 64)] = v;
                else               vsl[rt * 16 + g * 4 + r][c - 128] = v;
            }
        }
    __syncthreads();
    {   // vt[b][h][seq] cooperative write: thread owns (h, 8-seq segment)
        const int h = tid >> 2, seg = tid & 3;
        short tmp[8];
        #pragma unroll
        for (int j = 0; j < 8; j++) tmp[j] = vsl[seg * 8 + j][h];
        bf16x8 o;
        #pragma unroll
        for (int jj = 0; jj < 8; jj++) o[jj] = tmp[jj];
        *(bf16x8*)(vtb + ((size_t)bi * 64 + h) * TT + sl0 + seg * 8) = o;
    }
}

// ---------------------------------------------------------------------------
// Flash attention v5 (unchanged from R5): swapped QK^T + in-register softmax,
// split-kv over 8 waves with LDS merge, software-pipelined K/V loads.
// ---------------------------------------------------------------------------
__global__ __launch_bounds__(512, 2)
void attn_kernel(
    const short* __restrict__ qb, const short* __restrict__ kb,
    const short* __restrict__ vtb, float* __restrict__ out)
{
    __shared__ __align__(16) char smem[AW * 4608];
    __shared__ float ml[AW][64];   // [w][0..31]=m, [w][32..63]=l

    const int tid  = threadIdx.x;
    const int w    = tid >> 6, lane = tid & 63;
    const int l15  = lane & 15, g = lane >> 4;
    const int b    = blockIdx.x & 7;
    const int qt   = 63 - (blockIdx.x >> 3);
    const int r0   = qt * 32;
    const int nkv  = (r0 >> 6) + 1;

    short* ps = (short*)(smem + w * 4608);   // [32][72]

    const short* q  = qb  + (size_t)b * TT * 64;
    const short* k  = kb  + (size_t)b * TT * 64;
    const short* vt = vtb + (size_t)b * 64 * TT;

    bf16x8 qf[2][2];
    #pragma unroll
    for (int rt = 0; rt < 2; rt++)
        #pragma unroll
        for (int kc = 0; kc < 2; kc++)
            qf[rt][kc] = *(const bf16x8*)(q + (size_t)(r0 + rt * 16 + l15) * 64 + kc * 32 + g * 8);

    f32x4 o[2][4];
    float m_[2] = { -INFINITY, -INFINITY };
    float l_[2] = { 0.f, 0.f };
    #pragma unroll
    for (int rt = 0; rt < 2; rt++)
        #pragma unroll
        for (int ht = 0; ht < 4; ht++) o[rt][ht] = (f32x4){0.f, 0.f, 0.f, 0.f};

    bf16x8 kf[4][2];
    if (w < nkv) {
        #pragma unroll
        for (int nt = 0; nt < 4; nt++)
            #pragma unroll
            for (int kc = 0; kc < 2; kc++)
                kf[nt][kc] = *(const bf16x8*)(
                    k + (size_t)(w * 64 + nt * 16 + l15) * 64 + kc * 32 + g * 8);
    }

    for (int t = w; t < nkv; t += AW) {
        const int s0 = t * 64;
        const bool diag = (t == nkv - 1);
        const bool more = (t + AW < nkv);

        f32x4 s[2][4];
        #pragma unroll
        for (int rt = 0; rt < 2; rt++)
            #pragma unroll
            for (int nt = 0; nt < 4; nt++) s[rt][nt] = (f32x4){0.f, 0.f, 0.f, 0.f};
        #pragma unroll
        for (int kc = 0; kc < 2; kc++)
            #pragma unroll
            for (int rt = 0; rt < 2; rt++)
                #pragma unroll
                for (int nt = 0; nt < 4; nt++)
                    s[rt][nt] = __builtin_amdgcn_mfma_f32_16x16x32_bf16(
                        kf[nt][kc], qf[rt][kc], s[rt][nt], 0, 0, 0);

        bf16x8 vf[4][2];
        #pragma unroll
        for (int ht = 0; ht < 4; ht++)
            #pragma unroll
            for (int kc = 0; kc < 2; kc++)
                vf[ht][kc] = *(const bf16x8*)(
                    vt + (size_t)(ht * 16 + l15) * TT + s0 + kc * 32 + g * 8);
        bf16x8 kfn[4][2];
        if (more) {
            #pragma unroll
            for (int nt = 0; nt < 4; nt++)
                #pragma unroll
                for (int kc = 0; kc < 2; kc++)
                    kfn[nt][kc] = *(const bf16x8*)(
                        k + (size_t)(s0 + AW * 64 + nt * 16 + l15) * 64 + kc * 32 + g * 8);
        }

        if (diag) {
            #pragma unroll
            for (int rt = 0; rt < 2; rt++) {
                const int qg = r0 + rt * 16 + l15;
                #pragma unroll
                for (int nt = 0; nt < 4; nt++)
                    #pragma unroll
                    for (int r = 0; r < 4; r++)
                        if (s0 + nt * 16 + g * 4 + r > qg) s[rt][nt][r] = -INFINITY;
            }
        }

        #pragma unroll
        for (int rt = 0; rt < 2; rt++) {
            float a0 = fmaxf(fmaxf(s[rt][0][0], s[rt][0][1]), fmaxf(s[rt][0][2], s[rt][0][3]));
            float a1 = fmaxf(fmaxf(s[rt][1][0], s[rt][1][1]), fmaxf(s[rt][1][2], s[rt][1][3]));
            float a2 = fmaxf(fmaxf(s[rt][2][0], s[rt][2][1]), fmaxf(s[rt][2][2], s[rt][2][3]));
            float a3 = fmaxf(fmaxf(s[rt][3][0], s[rt][3][1]), fmaxf(s[rt][3][2], s[rt][3][3]));
            float tm = fmaxf(fmaxf(a0, a1), fmaxf(a2, a3));
            tm = fmaxf(tm, __shfl_xor(tm, 16));
            tm = fmaxf(tm, __shfl_xor(tm, 32));

            const float mn = fmaxf(m_[rt], tm);
            const float al = __builtin_amdgcn_exp2f(m_[rt] - mn);
            m_[rt] = mn;

            #pragma unroll
            for (int nt = 0; nt < 4; nt++)
                #pragma unroll
                for (int r = 0; r < 4; r++)
                    s[rt][nt][r] = __builtin_amdgcn_exp2f(s[rt][nt][r] - mn);

            float b0 = (s[rt][0][0] + s[rt][0][1]) + (s[rt][0][2] + s[rt][0][3]);
            float b1 = (s[rt][1][0] + s[rt][1][1]) + (s[rt][1][2] + s[rt][1][3]);
            float b2 = (s[rt][2][0] + s[rt][2][1]) + (s[rt][2][2] + s[rt][2][3]);
            float b3 = (s[rt][3][0] + s[rt][3][1]) + (s[rt][3][2] + s[rt][3][3]);
            float ts = (b0 + b1) + (b2 + b3);
            ts += __shfl_xor(ts, 16);
            ts += __shfl_xor(ts, 32);
            l_[rt] = l_[rt] * al + ts;

            float ab[4];
            #pragma unroll
            for (int r = 0; r < 4; r++) ab[r] = __shfl(al, g * 4 + r);
            #pragma unroll
            for (int ht = 0; ht < 4; ht++)
                #pragma unroll
                for (int r = 0; r < 4; r++)
                    o[rt][ht][r] *= ab[r];

            #pragma unroll
            for (int nt = 0; nt < 4; nt++) {
                s16x4 pk = { f2bf(s[rt][nt][0]), f2bf(s[rt][nt][1]),
                             f2bf(s[rt][nt][2]), f2bf(s[rt][nt][3]) };
                *(s16x4*)&ps[(rt * 16 + l15) * 72 + nt * 16 + g * 4] = pk;
            }
        }

        bf16x8 pf[2][2];
        #pragma unroll
        for (int rt = 0; rt < 2; rt++)
            #pragma unroll
            for (int kc = 0; kc < 2; kc++)
                pf[rt][kc] = *(const bf16x8*)&ps[(rt * 16 + l15) * 72 + kc * 32 + g * 8];
        #pragma unroll
        for (int kc = 0; kc < 2; kc++)
            #pragma unroll
            for (int rt = 0; rt < 2; rt++)
                #pragma unroll
                for (int ht = 0; ht < 4; ht++)
                    o[rt][ht] = __builtin_amdgcn_mfma_f32_16x16x32_bf16(
                        pf[rt][kc], vf[ht][kc], o[rt][ht], 0, 0, 0);

        if (more) {
            #pragma unroll
            for (int nt = 0; nt < 4; nt++)
                #pragma unroll
                for (int kc = 0; kc < 2; kc++)
                    kf[nt][kc] = kfn[nt][kc];
        }
    }

    if (g == 0) {
        #pragma unroll
        for (int rt = 0; rt < 2; rt++) {
            ml[w][rt * 16 + l15]      = m_[rt];
            ml[w][32 + rt * 16 + l15] = l_[rt];
        }
    }
    short* pO = ps;   // [32][68] bf16 (ps is dead now)
    #pragma unroll
    for (int rt = 0; rt < 2; rt++)
        #pragma unroll
        for (int ht = 0; ht < 4; ht++)
            #pragma unroll
            for (int r = 0; r < 4; r++)
                pO[(rt * 16 + g * 4 + r) * 68 + ht * 16 + l15] = f2bf(o[rt][ht][r]);
    __syncthreads();

    {
        const int row = tid >> 4, seg = tid & 15;
        float gm = -INFINITY;
        #pragma unroll
        for (int w2 = 0; w2 < AW; w2++) gm = fmaxf(gm, ml[w2][row]);
        float accL = 0.f;
        float accO[4] = {0.f, 0.f, 0.f, 0.f};
        #pragma unroll
        for (int w2 = 0; w2 < AW; w2++) {
            const float sc = __builtin_amdgcn_exp2f(ml[w2][row] - gm);
            accL = fmaf(sc, ml[w2][32 + row], accL);
            const s16x4 ov = *(const s16x4*)((const short*)(smem + w2 * 4608) + row * 68 + seg * 4);
            #pragma unroll
            for (int j = 0; j < 4; j++)
                accO[j] = fmaf(sc, bf2f(ov[j]), accO[j]);
        }
        const float inv = 1.f / accL;
        float4 res = make_float4(accO[0] * inv, accO[1] * inv, accO[2] * inv, accO[3] * inv);
        *(float4*)(out + ((size_t)b * TT + r0 + row) * 64 + seg * 4) = res;
    }
}

extern "C" void kernel_launch(void* const* d_in, const int* in_sizes, int n_in,
                              void* d_out, int out_size, void* d_ws, size_t ws_size,
                              hipStream_t stream) {
    const float* x  = (const float*)d_in[0];
    const float* Wk = (const float*)d_in[1];
    const float* Wq = (const float*)d_in[2];
    const float* Wv = (const float*)d_in[3];
    float* outp = (float*)d_out;

    short* wt  = (short*)d_ws;                     // [192][1024] bf16
    short* qb  = wt + (size_t)192 * 1024;          // [16384][64] bf16 (pre-scaled)
    short* kb  = qb + (size_t)MROWS * 64;          // [16384][64] bf16
    short* vtb = kb + (size_t)MROWS * 64;          // [8][64][2048] bf16 (V^T)

    wtrans_kernel<<<48, 256, 0, stream>>>(Wk, Wq, Wv, wt);
    proj_kernel<<<MROWS / 32, 256, 0, stream>>>(x, wt, qb, kb, vtb);
    attn_kernel<<<BATCH * 64, 512, 0, stream>>>(qb, kb, vtb, outp);
}

// Round 7
// 61.665 us; speedup vs baseline: 1.3681x; 1.3681x over previous
//
#include <hip/hip_runtime.h>
#include <hip/hip_bf16.h>

#define TT 2048
#define BATCH 8
#define MROWS (BATCH*TT)   // 16384
#define AW 8               // waves per attn block

typedef __attribute__((ext_vector_type(8))) short bf16x8;   // MFMA A/B frag (4 VGPR)
typedef __attribute__((ext_vector_type(4))) short s16x4;
typedef __attribute__((ext_vector_type(4))) float f32x4;    // MFMA C/D frag

__device__ __forceinline__ short f2bf(float f) {
    union { __hip_bfloat16 h; short s; } u;
    u.h = __float2bfloat16(f);
    return u.s;
}
__device__ __forceinline__ float bf2f(short s) {
    union { unsigned u; float f; } u;
    u.u = ((unsigned)(unsigned short)s) << 16;
    return u.f;
}

// ---------------------------------------------------------------------------
// W transpose: Wq|Wk|Wv [1024][64] f32 -> wt [192][1024] bf16 (row n = col of W)
// Wq gets scale = (1/32)*log2(e) folded in (softmax scale + exp->exp2).
// ---------------------------------------------------------------------------
__global__ __launch_bounds__(256) void wtrans_kernel(
    const float* __restrict__ Wk, const float* __restrict__ Wq,
    const float* __restrict__ Wv, short* __restrict__ wt)
{
    __shared__ float tile[64][68];
    const int mat = blockIdx.x >> 4;           // 0=q,1=k,2=v
    const int k0  = (blockIdx.x & 15) * 64;
    const float* W = (mat == 0) ? Wq : (mat == 1) ? Wk : Wv;
    const float scl = (mat == 0) ? 0.04508422002778011f : 1.0f;  // (1/32)*log2(e)
    const int t = threadIdx.x;
    const int row = t >> 2, quad = t & 3;
    #pragma unroll
    for (int i = 0; i < 4; i++) {
        float4 v = *(const float4*)(W + (size_t)(k0 + row) * 64 + quad * 16 + i * 4);
        *(float4*)&tile[row][quad * 16 + i * 4] = v;
    }
    __syncthreads();
    short tmp[16];
    #pragma unroll
    for (int j = 0; j < 16; j++) tmp[j] = f2bf(tile[quad * 16 + j][row] * scl);
    short* dst = wt + (size_t)(mat * 64 + row) * 1024 + k0 + quad * 16;
    #pragma unroll
    for (int j2 = 0; j2 < 2; j2++) {
        bf16x8 o;
        #pragma unroll
        for (int jj = 0; jj < 8; jj++) o[jj] = tmp[j2 * 8 + jj];
        *(bf16x8*)(dst + j2 * 8) = o;
    }
}

// ---------------------------------------------------------------------------
// Projection v4: BM=32, 512 threads (8 waves), SPLIT-K.
// Wave w: k-half h = w>>2 (512 k each, 8 steps of 64), col-slice cg = w&3
// (48 cols). x staged to LDS bf16 (coalesced, double-buffered, barriers pin
// the pipeline); wt frags direct from L2. Partial accs reduced through LDS.
// launch_bounds(512,4): 2 blocks/CU -> 16 waves/CU TLP, VGPR cap 128.
// ---------------------------------------------------------------------------
__global__ __launch_bounds__(512, 4) void proj_kernel(
    const float* __restrict__ x, const short* __restrict__ wt,
    short* __restrict__ qb, short* __restrict__ kb, short* __restrict__ vtb)
{
    __shared__ short xs[2][2][32][72];   // [buf][half][row][k] bf16, 18 KB
    __shared__ float red[4][32][48];     // split-K reduction, 24 KB
    __shared__ short vsl[32][66];        // V transpose staging, 4.2 KB

    const int tid  = threadIdx.x;
    const int lane = tid & 63, w = tid >> 6;
    const int l15  = lane & 15, g = lane >> 4;
    const int r0   = blockIdx.x * 32;
    const int h    = w >> 2;             // k-half (0/1)
    const int cg   = w & 3;              // col-group: cols [cg*48, cg*48+48)

    // staging: thread t owns float4 (row=t>>4, c4=t&15) in BOTH halves
    const int srow = tid >> 4, sc4 = tid & 15;
    const float* xsrc = x + (size_t)(r0 + srow) * 1024 + sc4 * 4;

    f32x4 acc[2][3];
    #pragma unroll
    for (int rt = 0; rt < 2; rt++)
        #pragma unroll
        for (int nt = 0; nt < 3; nt++)
            acc[rt][nt] = (f32x4){0.f, 0.f, 0.f, 0.f};

    // prologue: stage step 0, prefetch step 1 into regs
    {
        float4 a0 = *(const float4*)(xsrc);
        float4 a1 = *(const float4*)(xsrc + 512);
        s16x4 s0v = { f2bf(a0.x), f2bf(a0.y), f2bf(a0.z), f2bf(a0.w) };
        s16x4 s1v = { f2bf(a1.x), f2bf(a1.y), f2bf(a1.z), f2bf(a1.w) };
        *(s16x4*)&xs[0][0][srow][sc4 * 4] = s0v;
        *(s16x4*)&xs[0][1][srow][sc4 * 4] = s1v;
    }
    float4 p0 = *(const float4*)(xsrc + 64);
    float4 p1 = *(const float4*)(xsrc + 512 + 64);
    __syncthreads();

    #pragma unroll
    for (int s = 0; s < 8; s++) {
        const int cur = s & 1;

        // wt frags for this step (L2-resident; wait lands at first MFMA)
        bf16x8 bfrag[3][2];
        #pragma unroll
        for (int nt = 0; nt < 3; nt++)
            #pragma unroll
            for (int kc = 0; kc < 2; kc++)
                bfrag[nt][kc] = *(const bf16x8*)(
                    wt + (size_t)(cg * 48 + nt * 16 + l15) * 1024
                       + h * 512 + s * 64 + kc * 32 + g * 8);

        // write prefetched step s+1 into the other buffer
        if (s < 7) {
            s16x4 s0v = { f2bf(p0.x), f2bf(p0.y), f2bf(p0.z), f2bf(p0.w) };
            s16x4 s1v = { f2bf(p1.x), f2bf(p1.y), f2bf(p1.z), f2bf(p1.w) };
            *(s16x4*)&xs[cur ^ 1][0][srow][sc4 * 4] = s0v;
            *(s16x4*)&xs[cur ^ 1][1][srow][sc4 * 4] = s1v;
        }
        // issue step s+2 loads (land during this step's MFMA + barrier wait)
        if (s < 6) {
            p0 = *(const float4*)(xsrc + (s + 2) * 64);
            p1 = *(const float4*)(xsrc + 512 + (s + 2) * 64);
        }

        // A-frags from this wave's k-half, then MFMA
        #pragma unroll
        for (int kc = 0; kc < 2; kc++) {
            bf16x8 af[2];
            #pragma unroll
            for (int rt = 0; rt < 2; rt++)
                af[rt] = *(const bf16x8*)&xs[cur][h][rt * 16 + l15][kc * 32 + g * 8];
            #pragma unroll
            for (int rt = 0; rt < 2; rt++)
                #pragma unroll
                for (int nt = 0; nt < 3; nt++)
                    acc[rt][nt] = __builtin_amdgcn_mfma_f32_16x16x32_bf16(
                        af[rt], bfrag[nt][kc], acc[rt][nt], 0, 0, 0);
        }
        __syncthreads();
    }

    // ---- split-K reduce: h==1 waves publish, h==0 waves accumulate
    if (h == 1) {
        #pragma unroll
        for (int rt = 0; rt < 2; rt++)
            #pragma unroll
            for (int nt = 0; nt < 3; nt++)
                #pragma unroll
                for (int r = 0; r < 4; r++)
                    red[cg][rt * 16 + g * 4 + r][nt * 16 + l15] = acc[rt][nt][r];
    }
    __syncthreads();

    const int bi  = r0 >> 11;
    const int sl0 = r0 & 2047;
    if (h == 0) {
        #pragma unroll
        for (int rt = 0; rt < 2; rt++)
            #pragma unroll
            for (int nt = 0; nt < 3; nt++) {
                const int c = cg * 48 + nt * 16 + l15;
                #pragma unroll
                for (int r = 0; r < 4; r++) {
                    const int row = r0 + rt * 16 + g * 4 + r;
                    const float sum = acc[rt][nt][r]
                                    + red[cg][rt * 16 + g * 4 + r][nt * 16 + l15];
                    const short v = f2bf(sum);
                    if (c < 64)        qb[(size_t)row * 64 + c] = v;
                    else if (c < 128)  kb[(size_t)row * 64 + (c - 64)] = v;
                    else               vsl[rt * 16 + g * 4 + r][c - 128] = v;
                }
            }
    }
    __syncthreads();
    {   // vt[b][col][seq] transposed write: thread owns (col, 4-row segment)
        const int col = tid >> 3, seg = tid & 7;
        s16x4 o = { vsl[seg * 4 + 0][col], vsl[seg * 4 + 1][col],
                    vsl[seg * 4 + 2][col], vsl[seg * 4 + 3][col] };
        *(s16x4*)(vtb + ((size_t)bi * 64 + col) * TT + sl0 + seg * 4) = o;
    }
}

// ---------------------------------------------------------------------------
// Flash attention v5 (unchanged from R5): swapped QK^T + in-register softmax,
// split-kv over 8 waves with LDS merge, software-pipelined K/V loads.
// ---------------------------------------------------------------------------
__global__ __launch_bounds__(512, 2)
void attn_kernel(
    const short* __restrict__ qb, const short* __restrict__ kb,
    const short* __restrict__ vtb, float* __restrict__ out)
{
    __shared__ __align__(16) char smem[AW * 4608];
    __shared__ float ml[AW][64];   // [w][0..31]=m, [w][32..63]=l

    const int tid  = threadIdx.x;
    const int w    = tid >> 6, lane = tid & 63;
    const int l15  = lane & 15, g = lane >> 4;
    const int b    = blockIdx.x & 7;
    const int qt   = 63 - (blockIdx.x >> 3);
    const int r0   = qt * 32;
    const int nkv  = (r0 >> 6) + 1;

    short* ps = (short*)(smem + w * 4608);   // [32][72]

    const short* q  = qb  + (size_t)b * TT * 64;
    const short* k  = kb  + (size_t)b * TT * 64;
    const short* vt = vtb + (size_t)b * 64 * TT;

    bf16x8 qf[2][2];
    #pragma unroll
    for (int rt = 0; rt < 2; rt++)
        #pragma unroll
        for (int kc = 0; kc < 2; kc++)
            qf[rt][kc] = *(const bf16x8*)(q + (size_t)(r0 + rt * 16 + l15) * 64 + kc * 32 + g * 8);

    f32x4 o[2][4];
    float m_[2] = { -INFINITY, -INFINITY };
    float l_[2] = { 0.f, 0.f };
    #pragma unroll
    for (int rt = 0; rt < 2; rt++)
        #pragma unroll
        for (int ht = 0; ht < 4; ht++) o[rt][ht] = (f32x4){0.f, 0.f, 0.f, 0.f};

    bf16x8 kf[4][2];
    if (w < nkv) {
        #pragma unroll
        for (int nt = 0; nt < 4; nt++)
            #pragma unroll
            for (int kc = 0; kc < 2; kc++)
                kf[nt][kc] = *(const bf16x8*)(
                    k + (size_t)(w * 64 + nt * 16 + l15) * 64 + kc * 32 + g * 8);
    }

    for (int t = w; t < nkv; t += AW) {
        const int s0 = t * 64;
        const bool diag = (t == nkv - 1);
        const bool more = (t + AW < nkv);

        f32x4 s[2][4];
        #pragma unroll
        for (int rt = 0; rt < 2; rt++)
            #pragma unroll
            for (int nt = 0; nt < 4; nt++) s[rt][nt] = (f32x4){0.f, 0.f, 0.f, 0.f};
        #pragma unroll
        for (int kc = 0; kc < 2; kc++)
            #pragma unroll
            for (int rt = 0; rt < 2; rt++)
                #pragma unroll
                for (int nt = 0; nt < 4; nt++)
                    s[rt][nt] = __builtin_amdgcn_mfma_f32_16x16x32_bf16(
                        kf[nt][kc], qf[rt][kc], s[rt][nt], 0, 0, 0);

        bf16x8 vf[4][2];
        #pragma unroll
        for (int ht = 0; ht < 4; ht++)
            #pragma unroll
            for (int kc = 0; kc < 2; kc++)
                vf[ht][kc] = *(const bf16x8*)(
                    vt + (size_t)(ht * 16 + l15) * TT + s0 + kc * 32 + g * 8);
        bf16x8 kfn[4][2];
        if (more) {
            #pragma unroll
            for (int nt = 0; nt < 4; nt++)
                #pragma unroll
                for (int kc = 0; kc < 2; kc++)
                    kfn[nt][kc] = *(const bf16x8*)(
                        k + (size_t)(s0 + AW * 64 + nt * 16 + l15) * 64 + kc * 32 + g * 8);
        }

        if (diag) {
            #pragma unroll
            for (int rt = 0; rt < 2; rt++) {
                const int qg = r0 + rt * 16 + l15;
                #pragma unroll
                for (int nt = 0; nt < 4; nt++)
                    #pragma unroll
                    for (int r = 0; r < 4; r++)
                        if (s0 + nt * 16 + g * 4 + r > qg) s[rt][nt][r] = -INFINITY;
            }
        }

        #pragma unroll
        for (int rt = 0; rt < 2; rt++) {
            float a0 = fmaxf(fmaxf(s[rt][0][0], s[rt][0][1]), fmaxf(s[rt][0][2], s[rt][0][3]));
            float a1 = fmaxf(fmaxf(s[rt][1][0], s[rt][1][1]), fmaxf(s[rt][1][2], s[rt][1][3]));
            float a2 = fmaxf(fmaxf(s[rt][2][0], s[rt][2][1]), fmaxf(s[rt][2][2], s[rt][2][3]));
            float a3 = fmaxf(fmaxf(s[rt][3][0], s[rt][3][1]), fmaxf(s[rt][3][2], s[rt][3][3]));
            float tm = fmaxf(fmaxf(a0, a1), fmaxf(a2, a3));
            tm = fmaxf(tm, __shfl_xor(tm, 16));
            tm = fmaxf(tm, __shfl_xor(tm, 32));

            const float mn = fmaxf(m_[rt], tm);
            const float al = __builtin_amdgcn_exp2f(m_[rt] - mn);
            m_[rt] = mn;

            #pragma unroll
            for (int nt = 0; nt < 4; nt++)
                #pragma unroll
                for (int r = 0; r < 4; r++)
                    s[rt][nt][r] = __builtin_amdgcn_exp2f(s[rt][nt][r] - mn);

            float b0 = (s[rt][0][0] + s[rt][0][1]) + (s[rt][0][2] + s[rt][0][3]);
            float b1 = (s[rt][1][0] + s[rt][1][1]) + (s[rt][1][2] + s[rt][1][3]);
            float b2 = (s[rt][2][0] + s[rt][2][1]) + (s[rt][2][2] + s[rt][2][3]);
            float b3 = (s[rt][3][0] + s[rt][3][1]) + (s[rt][3][2] + s[rt][3][3]);
            float ts = (b0 + b1) + (b2 + b3);
            ts += __shfl_xor(ts, 16);
            ts += __shfl_xor(ts, 32);
            l_[rt] = l_[rt] * al + ts;

            float ab[4];
            #pragma unroll
            for (int r = 0; r < 4; r++) ab[r] = __shfl(al, g * 4 + r);
            #pragma unroll
            for (int ht = 0; ht < 4; ht++)
                #pragma unroll
                for (int r = 0; r < 4; r++)
                    o[rt][ht][r] *= ab[r];

            #pragma unroll
            for (int nt = 0; nt < 4; nt++) {
                s16x4 pk = { f2bf(s[rt][nt][0]), f2bf(s[rt][nt][1]),
                             f2bf(s[rt][nt][2]), f2bf(s[rt][nt][3]) };
                *(s16x4*)&ps[(rt * 16 + l15) * 72 + nt * 16 + g * 4] = pk;
            }
        }

        bf16x8 pf[2][2];
        #pragma unroll
        for (int rt = 0; rt < 2; rt++)
            #pragma unroll
            for (int kc = 0; kc < 2; kc++)
                pf[rt][kc] = *(const bf16x8*)&ps[(rt * 16 + l15) * 72 + kc * 32 + g * 8];
        #pragma unroll
        for (int kc = 0; kc < 2; kc++)
            #pragma unroll
            for (int rt = 0; rt < 2; rt++)
                #pragma unroll
                for (int ht = 0; ht < 4; ht++)
                    o[rt][ht] = __builtin_amdgcn_mfma_f32_16x16x32_bf16(
                        pf[rt][kc], vf[ht][kc], o[rt][ht], 0, 0, 0);

        if (more) {
            #pragma unroll
            for (int nt = 0; nt < 4; nt++)
                #pragma unroll
                for (int kc = 0; kc < 2; kc++)
                    kf[nt][kc] = kfn[nt][kc];
        }
    }

    if (g == 0) {
        #pragma unroll
        for (int rt = 0; rt < 2; rt++) {
            ml[w][rt * 16 + l15]      = m_[rt];
            ml[w][32 + rt * 16 + l15] = l_[rt];
        }
    }
    short* pO = ps;   // [32][68] bf16 (ps is dead now)
    #pragma unroll
    for (int rt = 0; rt < 2; rt++)
        #pragma unroll
        for (int ht = 0; ht < 4; ht++)
            #pragma unroll
            for (int r = 0; r < 4; r++)
                pO[(rt * 16 + g * 4 + r) * 68 + ht * 16 + l15] = f2bf(o[rt][ht][r]);
    __syncthreads();

    {
        const int row = tid >> 4, seg = tid & 15;
        float gm = -INFINITY;
        #pragma unroll
        for (int w2 = 0; w2 < AW; w2++) gm = fmaxf(gm, ml[w2][row]);
        float accL = 0.f;
        float accO[4] = {0.f, 0.f, 0.f, 0.f};
        #pragma unroll
        for (int w2 = 0; w2 < AW; w2++) {
            const float sc = __builtin_amdgcn_exp2f(ml[w2][row] - gm);
            accL = fmaf(sc, ml[w2][32 + row], accL);
            const s16x4 ov = *(const s16x4*)((const short*)(smem + w2 * 4608) + row * 68 + seg * 4);
            #pragma unroll
            for (int j = 0; j < 4; j++)
                accO[j] = fmaf(sc, bf2f(ov[j]), accO[j]);
        }
        const float inv = 1.f / accL;
        float4 res = make_float4(accO[0] * inv, accO[1] * inv, accO[2] * inv, accO[3] * inv);
        *(float4*)(out + ((size_t)b * TT + r0 + row) * 64 + seg * 4) = res;
    }
}

extern "C" void kernel_launch(void* const* d_in, const int* in_sizes, int n_in,
                              void* d_out, int out_size, void* d_ws, size_t ws_size,
                              hipStream_t stream) {
    const float* x  = (const float*)d_in[0];
    const float* Wk = (const float*)d_in[1];
    const float* Wq = (const float*)d_in[2];
    const float* Wv = (const float*)d_in[3];
    float* outp = (float*)d_out;

    short* wt  = (short*)d_ws;                     // [192][1024] bf16
    short* qb  = wt + (size_t)192 * 1024;          // [16384][64] bf16 (pre-scaled)
    short* kb  = qb + (size_t)MROWS * 64;          // [16384][64] bf16
    short* vtb = kb + (size_t)MROWS * 64;          // [8][64][2048] bf16 (V^T)

    wtrans_kernel<<<48, 256, 0, stream>>>(Wk, Wq, Wv, wt);
    proj_kernel<<<MROWS / 32, 512, 0, stream>>>(x, wt, qb, kb, vtb);
    attn_kernel<<<BATCH * 64, 512, 0, stream>>>(qb, kb, vtb, outp);
}

// Round 8
// 47.214 us; speedup vs baseline: 1.7869x; 1.3061x over previous
//
#include <hip/hip_runtime.h>
#include <hip/hip_bf16.h>

#define TT 2048
#define BATCH 8
#define MROWS (BATCH*TT)   // 16384
#define AW 8               // waves per attn block

typedef __attribute__((ext_vector_type(8))) short bf16x8;   // MFMA A/B frag (4 VGPR)
typedef __attribute__((ext_vector_type(4))) short s16x4;
typedef __attribute__((ext_vector_type(4))) float f32x4;    // MFMA C/D frag

__device__ __forceinline__ short f2bf(float f) {
    union { __hip_bfloat16 h; short s; } u;
    u.h = __float2bfloat16(f);
    return u.s;
}
__device__ __forceinline__ float bf2f(short s) {
    union { unsigned u; float f; } u;
    u.u = ((unsigned)(unsigned short)s) << 16;
    return u.f;
}

typedef __attribute__((address_space(3))) unsigned int       lds_u32_t;
typedef const __attribute__((address_space(1))) unsigned int g_u32_t;
__device__ __forceinline__ void gl_lds16(const void* g, void* l) {
    __builtin_amdgcn_global_load_lds((g_u32_t*)g, (lds_u32_t*)l, 16, 0, 0);
}

// ---------------------------------------------------------------------------
// W transpose: Wq|Wk|Wv [1024][64] f32 -> wt [192][1024] bf16 (row n = col of W)
// Wq gets scale = (1/32)*log2(e) folded in (softmax scale + exp->exp2).
// ---------------------------------------------------------------------------
__global__ __launch_bounds__(256) void wtrans_kernel(
    const float* __restrict__ Wk, const float* __restrict__ Wq,
    const float* __restrict__ Wv, short* __restrict__ wt)
{
    __shared__ float tile[64][68];
    const int mat = blockIdx.x >> 4;           // 0=q,1=k,2=v
    const int k0  = (blockIdx.x & 15) * 64;
    const float* W = (mat == 0) ? Wq : (mat == 1) ? Wk : Wv;
    const float scl = (mat == 0) ? 0.04508422002778011f : 1.0f;  // (1/32)*log2(e)
    const int t = threadIdx.x;
    const int row = t >> 2, quad = t & 3;
    #pragma unroll
    for (int i = 0; i < 4; i++) {
        float4 v = *(const float4*)(W + (size_t)(k0 + row) * 64 + quad * 16 + i * 4);
        *(float4*)&tile[row][quad * 16 + i * 4] = v;
    }
    __syncthreads();
    short tmp[16];
    #pragma unroll
    for (int j = 0; j < 16; j++) tmp[j] = f2bf(tile[quad * 16 + j][row] * scl);
    short* dst = wt + (size_t)(mat * 64 + row) * 1024 + k0 + quad * 16;
    #pragma unroll
    for (int j2 = 0; j2 < 2; j2++) {
        bf16x8 o;
        #pragma unroll
        for (int jj = 0; jj < 8; jj++) o[jj] = tmp[j2 * 8 + jj];
        *(bf16x8*)(dst + j2 * 8) = o;
    }
}

// ---------------------------------------------------------------------------
// Projection v5 (m97 structure): BM=32, BN=192, BK=64, 256 thr, 512 blocks.
// Both operands staged via async global_load_lds(16B): A = x tile fp32
// (converted at frag read), B = wt tile bf16. XOR bank-swizzle done per
// rule 21: linear LDS dest + inverse-swizzled per-lane GLOBAL source +
// swizzled LDS read. 2-phase loop: stage(t+1) -> compute(t) -> barrier
// (the compiler's vmcnt(0) drain at the barrier = exactly one hidden
// staging round-trip per step, not a killed register pipeline).
// Wave grid 2x2: wave owns 16 rows x 96 cols. LDS 64 KB -> 2 blocks/CU.
// ---------------------------------------------------------------------------
__global__ __launch_bounds__(256, 2) void proj_kernel(
    const float* __restrict__ x, const short* __restrict__ wt,
    short* __restrict__ qb, short* __restrict__ kb, short* __restrict__ vtb)
{
    // [0,16384): As [2][32][64] f32 (8192 B/buf)
    // [16384,65536): Bs [2][192][64] bf16 (24576 B/buf)
    __shared__ __align__(16) char lds[65536];

    const int tid  = threadIdx.x;
    const int lane = tid & 63, w = tid >> 6;
    const int l15  = lane & 15, g = lane >> 4;
    const int x7   = l15 & 7;
    const int wr   = w & 1;              // row group: rows wr*16..+15
    const int wc   = w >> 1;             // col group: cols wc*96..+95
    const int r0   = blockIdx.x * 32;

    // ---- staging addresses (per-lane global src pre-swizzled; LDS linear)
    const float* ag[2]; unsigned aOff[2];
    #pragma unroll
    for (int j = 0; j < 2; j++) {
        const int jp   = w * 2 + j;                 // issue 0..7, 4 rows each
        const int row  = jp * 4 + (lane >> 4);
        const int slot = (lane & 15) ^ (row & 7);
        ag[j]   = x + (size_t)(r0 + row) * 1024 + slot * 4;
        aOff[j] = jp * 1024;
    }
    const short* bg[6]; unsigned bOff[6];
    #pragma unroll
    for (int j = 0; j < 6; j++) {
        const int jp   = w * 6 + j;                 // issue 0..23, 8 rows each
        const int row  = jp * 8 + (lane >> 3);
        const int slot = (lane & 7) ^ (row & 7);
        bg[j]   = wt + (size_t)row * 1024 + slot * 8;
        bOff[j] = jp * 1024;
    }

    f32x4 acc[6];
    #pragma unroll
    for (int nt = 0; nt < 6; nt++) acc[nt] = (f32x4){0.f, 0.f, 0.f, 0.f};

    // prologue: stage k-tile 0 into buffer 0
    #pragma unroll
    for (int j = 0; j < 2; j++) gl_lds16(ag[j], lds + aOff[j]);
    #pragma unroll
    for (int j = 0; j < 6; j++) gl_lds16(bg[j], lds + 16384 + bOff[j]);
    __syncthreads();

    #pragma unroll
    for (int ks = 0; ks < 16; ks++) {
        const int cur = ks & 1;

        // issue async staging for next tile (lands by end-of-step barrier)
        if (ks < 15) {
            const int nb = cur ^ 1;
            #pragma unroll
            for (int j = 0; j < 2; j++)
                gl_lds16(ag[j] + (ks + 1) * 64, lds + nb * 8192 + aOff[j]);
            #pragma unroll
            for (int j = 0; j < 6; j++)
                gl_lds16(bg[j] + (ks + 1) * 64, lds + 16384 + nb * 24576 + bOff[j]);
        }

        const float* Ab = (const float*)(lds + cur * 8192);
        const short* Bb = (const short*)(lds + 16384 + cur * 24576);

        // A frags: fp32 from LDS (swizzled slots), convert to bf16
        bf16x8 af[2];
        #pragma unroll
        for (int kc = 0; kc < 2; kc++) {
            const int arow = wr * 16 + l15;
            f32x4 lo = *(const f32x4*)(Ab + arow * 64 + ((kc * 8 + 2 * g)     ^ x7) * 4);
            f32x4 hi = *(const f32x4*)(Ab + arow * 64 + ((kc * 8 + 2 * g + 1) ^ x7) * 4);
            af[kc] = (bf16x8){ f2bf(lo[0]), f2bf(lo[1]), f2bf(lo[2]), f2bf(lo[3]),
                               f2bf(hi[0]), f2bf(hi[1]), f2bf(hi[2]), f2bf(hi[3]) };
        }
        // B frags (bf16, swizzled slots)
        bf16x8 bfr[6][2];
        #pragma unroll
        for (int nt = 0; nt < 6; nt++)
            #pragma unroll
            for (int kc = 0; kc < 2; kc++)
                bfr[nt][kc] = *(const bf16x8*)(
                    Bb + (wc * 96 + nt * 16 + l15) * 64 + ((kc * 4 + g) ^ x7) * 8);

        #pragma unroll
        for (int kc = 0; kc < 2; kc++)
            #pragma unroll
            for (int nt = 0; nt < 6; nt++)
                acc[nt] = __builtin_amdgcn_mfma_f32_16x16x32_bf16(
                    af[kc], bfr[nt][kc], acc[nt], 0, 0, 0);

        __syncthreads();
    }

    // ---- epilogue: q,k direct; v via LDS transpose (overlay on As region)
    const int bi  = r0 >> 11;
    const int sl0 = r0 & 2047;
    short* vsl = (short*)lds;            // [32][66]
    #pragma unroll
    for (int nt = 0; nt < 6; nt++) {
        const int c = wc * 96 + nt * 16 + l15;
        #pragma unroll
        for (int r = 0; r < 4; r++) {
            const int row = r0 + wr * 16 + g * 4 + r;
            const short v = f2bf(acc[nt][r]);
            if (c < 64)        qb[(size_t)row * 64 + c] = v;
            else if (c < 128)  kb[(size_t)row * 64 + (c - 64)] = v;
            else               vsl[(wr * 16 + g * 4 + r) * 66 + (c - 128)] = v;
        }
    }
    __syncthreads();
    {   // vt[b][col][seq]: thread owns (col, 8-seq segment)
        const int col = tid >> 2, seg = tid & 3;
        short tmp[8];
        #pragma unroll
        for (int j = 0; j < 8; j++) tmp[j] = vsl[(seg * 8 + j) * 66 + col];
        bf16x8 o;
        #pragma unroll
        for (int jj = 0; jj < 8; jj++) o[jj] = tmp[jj];
        *(bf16x8*)(vtb + ((size_t)bi * 64 + col) * TT + sl0 + seg * 8) = o;
    }
}

// ---------------------------------------------------------------------------
// Flash attention v5 (unchanged from R5): swapped QK^T + in-register softmax,
// split-kv over 8 waves with LDS merge, software-pipelined K/V loads.
// ---------------------------------------------------------------------------
__global__ __launch_bounds__(512, 2)
void attn_kernel(
    const short* __restrict__ qb, const short* __restrict__ kb,
    const short* __restrict__ vtb, float* __restrict__ out)
{
    __shared__ __align__(16) char smem[AW * 4608];
    __shared__ float ml[AW][64];   // [w][0..31]=m, [w][32..63]=l

    const int tid  = threadIdx.x;
    const int w    = tid >> 6, lane = tid & 63;
    const int l15  = lane & 15, g = lane >> 4;
    const int b    = blockIdx.x & 7;
    const int qt   = 63 - (blockIdx.x >> 3);
    const int r0   = qt * 32;
    const int nkv  = (r0 >> 6) + 1;

    short* ps = (short*)(smem + w * 4608);   // [32][72]

    const short* q  = qb  + (size_t)b * TT * 64;
    const short* k  = kb  + (size_t)b * TT * 64;
    const short* vt = vtb + (size_t)b * 64 * TT;

    bf16x8 qf[2][2];
    #pragma unroll
    for (int rt = 0; rt < 2; rt++)
        #pragma unroll
        for (int kc = 0; kc < 2; kc++)
            qf[rt][kc] = *(const bf16x8*)(q + (size_t)(r0 + rt * 16 + l15) * 64 + kc * 32 + g * 8);

    f32x4 o[2][4];
    float m_[2] = { -INFINITY, -INFINITY };
    float l_[2] = { 0.f, 0.f };
    #pragma unroll
    for (int rt = 0; rt < 2; rt++)
        #pragma unroll
        for (int ht = 0; ht < 4; ht++) o[rt][ht] = (f32x4){0.f, 0.f, 0.f, 0.f};

    bf16x8 kf[4][2];
    if (w < nkv) {
        #pragma unroll
        for (int nt = 0; nt < 4; nt++)
            #pragma unroll
            for (int kc = 0; kc < 2; kc++)
                kf[nt][kc] = *(const bf16x8*)(
                    k + (size_t)(w * 64 + nt * 16 + l15) * 64 + kc * 32 + g * 8);
    }

    for (int t = w; t < nkv; t += AW) {
        const int s0 = t * 64;
        const bool diag = (t == nkv - 1);
        const bool more = (t + AW < nkv);

        f32x4 s[2][4];
        #pragma unroll
        for (int rt = 0; rt < 2; rt++)
            #pragma unroll
            for (int nt = 0; nt < 4; nt++) s[rt][nt] = (f32x4){0.f, 0.f, 0.f, 0.f};
        #pragma unroll
        for (int kc = 0; kc < 2; kc++)
            #pragma unroll
            for (int rt = 0; rt < 2; rt++)
                #pragma unroll
                for (int nt = 0; nt < 4; nt++)
                    s[rt][nt] = __builtin_amdgcn_mfma_f32_16x16x32_bf16(
                        kf[nt][kc], qf[rt][kc], s[rt][nt], 0, 0, 0);

        bf16x8 vf[4][2];
        #pragma unroll
        for (int ht = 0; ht < 4; ht++)
            #pragma unroll
            for (int kc = 0; kc < 2; kc++)
                vf[ht][kc] = *(const bf16x8*)(
                    vt + (size_t)(ht * 16 + l15) * TT + s0 + kc * 32 + g * 8);
        bf16x8 kfn[4][2];
        if (more) {
            #pragma unroll
            for (int nt = 0; nt < 4; nt++)
                #pragma unroll
                for (int kc = 0; kc < 2; kc++)
                    kfn[nt][kc] = *(const bf16x8*)(
                        k + (size_t)(s0 + AW * 64 + nt * 16 + l15) * 64 + kc * 32 + g * 8);
        }

        if (diag) {
            #pragma unroll
            for (int rt = 0; rt < 2; rt++) {
                const int qg = r0 + rt * 16 + l15;
                #pragma unroll
                for (int nt = 0; nt < 4; nt++)
                    #pragma unroll
                    for (int r = 0; r < 4; r++)
                        if (s0 + nt * 16 + g * 4 + r > qg) s[rt][nt][r] = -INFINITY;
            }
        }

        #pragma unroll
        for (int rt = 0; rt < 2; rt++) {
            float a0 = fmaxf(fmaxf(s[rt][0][0], s[rt][0][1]), fmaxf(s[rt][0][2], s[rt][0][3]));
            float a1 = fmaxf(fmaxf(s[rt][1][0], s[rt][1][1]), fmaxf(s[rt][1][2], s[rt][1][3]));
            float a2 = fmaxf(fmaxf(s[rt][2][0], s[rt][2][1]), fmaxf(s[rt][2][2], s[rt][2][3]));
            float a3 = fmaxf(fmaxf(s[rt][3][0], s[rt][3][1]), fmaxf(s[rt][3][2], s[rt][3][3]));
            float tm = fmaxf(fmaxf(a0, a1), fmaxf(a2, a3));
            tm = fmaxf(tm, __shfl_xor(tm, 16));
            tm = fmaxf(tm, __shfl_xor(tm, 32));

            const float mn = fmaxf(m_[rt], tm);
            const float al = __builtin_amdgcn_exp2f(m_[rt] - mn);
            m_[rt] = mn;

            #pragma unroll
            for (int nt = 0; nt < 4; nt++)
                #pragma unroll
                for (int r = 0; r < 4; r++)
                    s[rt][nt][r] = __builtin_amdgcn_exp2f(s[rt][nt][r] - mn);

            float b0 = (s[rt][0][0] + s[rt][0][1]) + (s[rt][0][2] + s[rt][0][3]);
            float b1 = (s[rt][1][0] + s[rt][1][1]) + (s[rt][1][2] + s[rt][1][3]);
            float b2 = (s[rt][2][0] + s[rt][2][1]) + (s[rt][2][2] + s[rt][2][3]);
            float b3 = (s[rt][3][0] + s[rt][3][1]) + (s[rt][3][2] + s[rt][3][3]);
            float ts = (b0 + b1) + (b2 + b3);
            ts += __shfl_xor(ts, 16);
            ts += __shfl_xor(ts, 32);
            l_[rt] = l_[rt] * al + ts;

            float ab[4];
            #pragma unroll
            for (int r = 0; r < 4; r++) ab[r] = __shfl(al, g * 4 + r);
            #pragma unroll
            for (int ht = 0; ht < 4; ht++)
                #pragma unroll
                for (int r = 0; r < 4; r++)
                    o[rt][ht][r] *= ab[r];

            #pragma unroll
            for (int nt = 0; nt < 4; nt++) {
                s16x4 pk = { f2bf(s[rt][nt][0]), f2bf(s[rt][nt][1]),
                             f2bf(s[rt][nt][2]), f2bf(s[rt][nt][3]) };
                *(s16x4*)&ps[(rt * 16 + l15) * 72 + nt * 16 + g * 4] = pk;
            }
        }

        bf16x8 pf[2][2];
        #pragma unroll
        for (int rt = 0; rt < 2; rt++)
            #pragma unroll
            for (int kc = 0; kc < 2; kc++)
                pf[rt][kc] = *(const bf16x8*)&ps[(rt * 16 + l15) * 72 + kc * 32 + g * 8];
        #pragma unroll
        for (int kc = 0; kc < 2; kc++)
            #pragma unroll
            for (int rt = 0; rt < 2; rt++)
                #pragma unroll
                for (int ht = 0; ht < 4; ht++)
                    o[rt][ht] = __builtin_amdgcn_mfma_f32_16x16x32_bf16(
                        pf[rt][kc], vf[ht][kc], o[rt][ht], 0, 0, 0);

        if (more) {
            #pragma unroll
            for (int nt = 0; nt < 4; nt++)
                #pragma unroll
                for (int kc = 0; kc < 2; kc++)
                    kf[nt][kc] = kfn[nt][kc];
        }
    }

    if (g == 0) {
        #pragma unroll
        for (int rt = 0; rt < 2; rt++) {
            ml[w][rt * 16 + l15]      = m_[rt];
            ml[w][32 + rt * 16 + l15] = l_[rt];
        }
    }
    short* pO = ps;   // [32][68] bf16 (ps is dead now)
    #pragma unroll
    for (int rt = 0; rt < 2; rt++)
        #pragma unroll
        for (int ht = 0; ht < 4; ht++)
            #pragma unroll
            for (int r = 0; r < 4; r++)
                pO[(rt * 16 + g * 4 + r) * 68 + ht * 16 + l15] = f2bf(o[rt][ht][r]);
    __syncthreads();

    {
        const int row = tid >> 4, seg = tid & 15;
        float gm = -INFINITY;
        #pragma unroll
        for (int w2 = 0; w2 < AW; w2++) gm = fmaxf(gm, ml[w2][row]);
        float accL = 0.f;
        float accO[4] = {0.f, 0.f, 0.f, 0.f};
        #pragma unroll
        for (int w2 = 0; w2 < AW; w2++) {
            const float sc = __builtin_amdgcn_exp2f(ml[w2][row] - gm);
            accL = fmaf(sc, ml[w2][32 + row], accL);
            const s16x4 ov = *(const s16x4*)((const short*)(smem + w2 * 4608) + row * 68 + seg * 4);
            #pragma unroll
            for (int j = 0; j < 4; j++)
                accO[j] = fmaf(sc, bf2f(ov[j]), accO[j]);
        }
        const float inv = 1.f / accL;
        float4 res = make_float4(accO[0] * inv, accO[1] * inv, accO[2] * inv, accO[3] * inv);
        *(float4*)(out + ((size_t)b * TT + r0 + row) * 64 + seg * 4) = res;
    }
}

extern "C" void kernel_launch(void* const* d_in, const int* in_sizes, int n_in,
                              void* d_out, int out_size, void* d_ws, size_t ws_size,
                              hipStream_t stream) {
    const float* x  = (const float*)d_in[0];
    const float* Wk = (const float*)d_in[1];
    const float* Wq = (const float*)d_in[2];
    const float* Wv = (const float*)d_in[3];
    float* outp = (float*)d_out;

    short* wt  = (short*)d_ws;                     // [192][1024] bf16
    short* qb  = wt + (size_t)192 * 1024;          // [16384][64] bf16 (pre-scaled)
    short* kb  = qb + (size_t)MROWS * 64;          // [16384][64] bf16
    short* vtb = kb + (size_t)MROWS * 64;          // [8][64][2048] bf16 (V^T)

    wtrans_kernel<<<48, 256, 0, stream>>>(Wk, Wq, Wv, wt);
    proj_kernel<<<MROWS / 32, 256, 0, stream>>>(x, wt, qb, kb, vtb);
    attn_kernel<<<BATCH * 64, 512, 0, stream>>>(qb, kb, vtb, outp);
}